// Round 1
// baseline (1108.101 us; speedup 1.0000x reference)
//
#include <hip/hip_runtime.h>
#include <cmath>

#define B 32
#define T 1024
#define CDIM 768
#define D 64
#define ROWS 32

// ---------------------------------------------------------------------------
// Kernel 1: fused QKV projection + RoPE.
// grid = B*T/ROWS blocks, block = 192 threads = 3 waves (wave0=Q, wave1=K,
// wave2=V). Each wave computes 32 rows x 64 cols of its projection.
// W loads: per-lane, coalesced (lane = col, stride 4B -> 256B/wave).
// x loads: wave-uniform address -> scalar (s_load_dwordx4) broadcasts.
// ---------------------------------------------------------------------------
__global__ __launch_bounds__(192) void proj_rope(
    const float* __restrict__ x,
    const float* __restrict__ Wq,
    const float* __restrict__ Wk,
    const float* __restrict__ Wv,
    float* __restrict__ qkv)   // [3][B*T][D] fp32
{
  const int lane = threadIdx.x & 63;
  const int sel  = threadIdx.x >> 6;          // 0=q 1=k 2=v (wave-uniform)
  const int row0 = blockIdx.x * ROWS;
  const float* W = (sel == 0) ? Wq : (sel == 1) ? Wk : Wv;

  float acc[ROWS];
  #pragma unroll
  for (int r = 0; r < ROWS; ++r) acc[r] = 0.f;

  for (int kk = 0; kk < CDIM; kk += 4) {
    float w0 = W[(kk + 0) * D + lane];
    float w1 = W[(kk + 1) * D + lane];
    float w2 = W[(kk + 2) * D + lane];
    float w3 = W[(kk + 3) * D + lane];
    #pragma unroll
    for (int r = 0; r < ROWS; ++r) {
      const float* xr = x + (size_t)(row0 + r) * CDIM + kk;  // wave-uniform
      acc[r] = fmaf(xr[0], w0, acc[r]);
      acc[r] = fmaf(xr[1], w1, acc[r]);
      acc[r] = fmaf(xr[2], w2, acc[r]);
      acc[r] = fmaf(xr[3], w3, acc[r]);
    }
  }

  float* outbase = qkv + (size_t)sel * (B * T * D);
  if (sel < 2) {
    // RoPE: pair (2i, 2i+1); even lane: te*cos - to*sin, odd: te*sin + to*cos
    const float sgn  = (lane & 1) ? 1.f : -1.f;
    // div_term[i] = exp(2i * -ln(10000)/64); lane&62 == 2i for both lanes
    const float freq = __expf((float)(lane & 62) * (-9.210340371976184f / (float)D));
    for (int r = 0; r < ROWS; ++r) {
      int trow = (row0 + r) & (T - 1);   // pos within sequence (blocks align to T)
      float theta = (float)trow * freq;
      float s = sinf(theta);
      float c = cosf(theta);
      float partner = __shfl_xor(acc[r], 1, 64);
      float val = fmaf(partner, sgn * s, acc[r] * c);
      outbase[(size_t)(row0 + r) * D + lane] = val;
    }
  } else {
    for (int r = 0; r < ROWS; ++r)
      outbase[(size_t)(row0 + r) * D + lane] = acc[r];
  }
}

// ---------------------------------------------------------------------------
// Kernel 2: causal flash attention, fp32.
// grid = (16 q-tiles, 32 batches), block = 256 threads.
// Thread t: query row i = t&63 (lane), col-group cg = t>>6 (wave-uniform).
// Q row in 64 VGPRs; K/V 64x64 tiles in LDS; scores round-trip LDS [j][i].
// ---------------------------------------------------------------------------
__global__ __launch_bounds__(256) void attn(
    const float* __restrict__ qg,
    const float* __restrict__ kg,
    const float* __restrict__ vg,
    float* __restrict__ out)
{
  const int qt = blockIdx.x;      // 0..15
  const int b  = blockIdx.y;      // 0..31
  const int t  = threadIdx.x;
  const int i  = t & 63;          // query row in tile (== lane)
  const int cg = t >> 6;          // 0..3, wave-uniform

  __shared__ float Kt[64 * 64];
  __shared__ float Vt[64 * 64];
  __shared__ float Sld[64 * 64];      // p stored [j][i]
  __shared__ float redmax[4 * 64];
  __shared__ float redsum[4 * 64];

  const float scale = 0.03608439182435161f;  // 1/sqrt(768)

  // Q row -> registers (16B/lane reads, one-time per block)
  float4 q4[16];
  {
    const float4* qrow = (const float4*)(qg + ((size_t)b * T + qt * 64 + i) * D);
    #pragma unroll
    for (int dc = 0; dc < 16; ++dc) q4[dc] = qrow[dc];
  }

  float4 O4[4];
  #pragma unroll
  for (int c = 0; c < 4; ++c) O4[c] = make_float4(0.f, 0.f, 0.f, 0.f);
  float mo = -1e30f, l = 0.f;

  for (int kt = 0; kt <= qt; ++kt) {
    __syncthreads();  // previous iteration's Kt/Vt/Sld readers done
    {
      const float4* kb = (const float4*)(kg + ((size_t)b * T + kt * 64) * D);
      const float4* vb = (const float4*)(vg + ((size_t)b * T + kt * 64) * D);
      float4* kl = (float4*)Kt;
      float4* vl = (float4*)Vt;
      #pragma unroll
      for (int r = 0; r < 4; ++r) {
        kl[r * 256 + t] = kb[r * 256 + t];
        vl[r * 256 + t] = vb[r * 256 + t];
      }
    }
    __syncthreads();

    // --- scores: 16 dots per thread, K rows broadcast from LDS ---
    float sc[16];
    float pmax = -1e30f;
    const bool diag = (kt == qt);
    #pragma unroll
    for (int jj = 0; jj < 16; ++jj) {
      const int j = cg * 16 + jj;
      const float4* kr = (const float4*)(Kt + j * 64);  // broadcast reads
      float a = 0.f;
      #pragma unroll
      for (int dc = 0; dc < 16; ++dc) {
        float4 k4 = kr[dc];
        a = fmaf(q4[dc].x, k4.x, a);
        a = fmaf(q4[dc].y, k4.y, a);
        a = fmaf(q4[dc].z, k4.z, a);
        a = fmaf(q4[dc].w, k4.w, a);
      }
      a *= scale;
      if (diag && j > i) a = -1e30f;   // causal mask (only on diagonal tile)
      sc[jj] = a;
      pmax = fmaxf(pmax, a);
    }

    // --- online softmax: cross-cgroup row max then sum ---
    redmax[cg * 64 + i] = pmax;
    __syncthreads();
    float mt = fmaxf(fmaxf(redmax[0 * 64 + i], redmax[1 * 64 + i]),
                     fmaxf(redmax[2 * 64 + i], redmax[3 * 64 + i]));
    float mn = fmaxf(mo, mt);
    float alpha = __expf(mo - mn);
    float psum = 0.f;
    #pragma unroll
    for (int jj = 0; jj < 16; ++jj) {
      float p = __expf(sc[jj] - mn);
      psum += p;
      Sld[(cg * 16 + jj) * 64 + i] = p;   // lane-consecutive writes
    }
    redsum[cg * 64 + i] = psum;
    __syncthreads();
    l = alpha * l + (redsum[0 * 64 + i] + redsum[1 * 64 + i] +
                     redsum[2 * 64 + i] + redsum[3 * 64 + i]);
    mo = mn;
    #pragma unroll
    for (int c = 0; c < 4; ++c) {
      O4[c].x *= alpha; O4[c].y *= alpha; O4[c].z *= alpha; O4[c].w *= alpha;
    }

    // --- PV: O[i][cg*16..+16) += sum_j p[i][j] * V[j][c] ---
    for (int j = 0; j < 64; ++j) {
      float p = Sld[j * 64 + i];                          // lane-consecutive
      const float4* vr = (const float4*)(Vt + j * 64 + cg * 16);  // broadcast
      #pragma unroll
      for (int c = 0; c < 4; ++c) {
        float4 v4 = vr[c];
        O4[c].x = fmaf(p, v4.x, O4[c].x);
        O4[c].y = fmaf(p, v4.y, O4[c].y);
        O4[c].z = fmaf(p, v4.z, O4[c].z);
        O4[c].w = fmaf(p, v4.w, O4[c].w);
      }
    }
  }

  const float inv = 1.f / l;
  float4* orow = (float4*)(out + ((size_t)b * T + qt * 64 + i) * D + cg * 16);
  #pragma unroll
  for (int c = 0; c < 4; ++c) {
    float4 o = O4[c];
    o.x *= inv; o.y *= inv; o.z *= inv; o.w *= inv;
    orow[c] = o;
  }
}

// ---------------------------------------------------------------------------
extern "C" void kernel_launch(void* const* d_in, const int* in_sizes, int n_in,
                              void* d_out, int out_size, void* d_ws, size_t ws_size,
                              hipStream_t stream) {
  const float* x  = (const float*)d_in[0];
  const float* Wq = (const float*)d_in[1];
  const float* Wk = (const float*)d_in[2];
  const float* Wv = (const float*)d_in[3];
  float* outp = (float*)d_out;
  float* qkv  = (float*)d_ws;   // needs 3*B*T*D*4 = 25.2 MB of workspace

  proj_rope<<<dim3((B * T) / ROWS), dim3(192), 0, stream>>>(x, Wq, Wk, Wv, qkv);
  attn<<<dim3(T / 64, B), dim3(256), 0, stream>>>(
      qkv, qkv + (size_t)B * T * D, qkv + 2 * (size_t)B * T * D, outp);
}

// Round 2
// 470.658 us; speedup vs baseline: 2.3544x; 2.3544x over previous
//
#include <hip/hip_runtime.h>
#include <cmath>

#define B 32
#define T 1024
#define CDIM 768
#define D 64

typedef short bf16x8 __attribute__((ext_vector_type(8)));   // 8 bf16 = 4 VGPRs
typedef float f32x4 __attribute__((ext_vector_type(4)));    // MFMA accumulator

__device__ inline ushort f2bf(float f) {
  union { float f; unsigned u; } v{f};
  unsigned r = (v.u + 0x7FFFu + ((v.u >> 16) & 1u)) >> 16;  // RNE
  return (ushort)r;
}

// ---------------------------------------------------------------------------
// Kernel 1: QKV projection as bf16 MFMA GEMM + fused RoPE.
// grid = (32768/128, 3 [q,k,v]); block = 256 threads = 4 waves.
// Block computes a 128x64 tile of sel's projection. Wave w: rows w*32..w*32+32,
// all 64 cols -> 2(M) x 4(N) tiles of mfma_f32_16x16x32_bf16.
// LDS: Xs[128][72] bf16 (pad 64->72: 2-way bank alias = free),
//      Ws[64][72] bf16, stored TRANSPOSED (Wt[n][k]) so B-frags read
//      8 contiguous k -> ds_read_b128.
// Fragment layouts (measured, learn_hip m89/m120):
//   A[m=lane&15][k=(lane>>4)*8+j], B[k=(lane>>4)*8+j][n=lane&15],
//   C/D: col=lane&15, row=(lane>>4)*4+reg.
// ---------------------------------------------------------------------------
#define XSTR 72
__global__ __launch_bounds__(256) void proj_mfma(
    const float* __restrict__ x,
    const float* __restrict__ Wq,
    const float* __restrict__ Wk,
    const float* __restrict__ Wv,
    float* __restrict__ qkv)   // [3][B*T][D] fp32
{
  const int t    = threadIdx.x;
  const int lane = t & 63;
  const int wid  = t >> 6;          // 0..3
  const int ln16 = lane & 15;
  const int quad = lane >> 4;       // 0..3
  const int sel  = blockIdx.y;      // 0=q 1=k 2=v
  const int row0 = blockIdx.x * 128;
  const float* W = (sel == 0) ? Wq : (sel == 1) ? Wk : Wv;

  __shared__ ushort Xs[128 * XSTR];
  __shared__ ushort Ws[64 * XSTR];

  f32x4 acc[2][4];
  #pragma unroll
  for (int mt = 0; mt < 2; ++mt)
    #pragma unroll
    for (int nt = 0; nt < 4; ++nt)
      acc[mt][nt] = (f32x4){0.f, 0.f, 0.f, 0.f};

  for (int stage = 0; stage < CDIM / 64; ++stage) {
    const int k0 = stage * 64;
    __syncthreads();   // prior k-step readers done before overwrite

    // --- stage x chunk: 128 rows x 64 k, fp32 -> bf16 ---
    #pragma unroll
    for (int it = 0; it < 8; ++it) {
      int slot = it * 256 + t;
      int row  = slot >> 4;
      int kq   = slot & 15;
      float4 xv = *(const float4*)(x + (size_t)(row0 + row) * CDIM + k0 + kq * 4);
      ushort4 bv;
      bv.x = f2bf(xv.x); bv.y = f2bf(xv.y); bv.z = f2bf(xv.z); bv.w = f2bf(xv.w);
      *(ushort4*)&Xs[row * XSTR + kq * 4] = bv;
    }
    // --- stage W chunk transposed: Wt[n][k], 64x64 ---
    #pragma unroll
    for (int it = 0; it < 4; ++it) {
      int slot = it * 256 + t;
      int k    = slot >> 4;
      int nq   = slot & 15;
      float4 wv = *(const float4*)(W + (size_t)(k0 + k) * D + nq * 4);
      Ws[(nq * 4 + 0) * XSTR + k] = f2bf(wv.x);
      Ws[(nq * 4 + 1) * XSTR + k] = f2bf(wv.y);
      Ws[(nq * 4 + 2) * XSTR + k] = f2bf(wv.z);
      Ws[(nq * 4 + 3) * XSTR + k] = f2bf(wv.w);
    }
    __syncthreads();

    #pragma unroll
    for (int ks = 0; ks < 2; ++ks) {
      const int koff = ks * 32 + quad * 8;
      bf16x8 a[2], bb[4];
      #pragma unroll
      for (int mt = 0; mt < 2; ++mt)
        a[mt] = *(const bf16x8*)&Xs[(wid * 32 + mt * 16 + ln16) * XSTR + koff];
      #pragma unroll
      for (int nt = 0; nt < 4; ++nt)
        bb[nt] = *(const bf16x8*)&Ws[(nt * 16 + ln16) * XSTR + koff];
      #pragma unroll
      for (int mt = 0; mt < 2; ++mt)
        #pragma unroll
        for (int nt = 0; nt < 4; ++nt)
          acc[mt][nt] = __builtin_amdgcn_mfma_f32_16x16x32_bf16(
              a[mt], bb[nt], acc[mt][nt], 0, 0, 0);
    }
  }

  // --- epilogue: RoPE (sel<2) + store ---
  float* outbase = qkv + (size_t)sel * (B * T * D);
  #pragma unroll
  for (int mt = 0; mt < 2; ++mt) {
    #pragma unroll
    for (int nt = 0; nt < 4; ++nt) {
      const int d = nt * 16 + ln16;
      if (sel < 2) {
        const float freq = __expf((float)(d & 62) * (-0.14391156855801f)); // ln(1e4)/64
        const float sgn  = (d & 1) ? 1.f : -1.f;
        #pragma unroll
        for (int reg = 0; reg < 4; ++reg) {
          int rowg = row0 + wid * 32 + mt * 16 + quad * 4 + reg;
          int tpos = rowg & (T - 1);
          float theta = (float)tpos * freq;
          float s = sinf(theta), c = cosf(theta);
          float val = acc[mt][nt][reg];
          float partner = __shfl_xor(val, 1, 64);
          outbase[(size_t)rowg * D + d] = fmaf(sgn * partner, s, val * c);
        }
      } else {
        #pragma unroll
        for (int reg = 0; reg < 4; ++reg) {
          int rowg = row0 + wid * 32 + mt * 16 + quad * 4 + reg;
          outbase[(size_t)rowg * D + d] = acc[mt][nt][reg];
        }
      }
    }
  }
}

// ---------------------------------------------------------------------------
// Kernel 2: causal flash attention, fp32 (unchanged from R1 — next target).
// ---------------------------------------------------------------------------
__global__ __launch_bounds__(256) void attn(
    const float* __restrict__ qg,
    const float* __restrict__ kg,
    const float* __restrict__ vg,
    float* __restrict__ out)
{
  const int qt = blockIdx.x;
  const int b  = blockIdx.y;
  const int t  = threadIdx.x;
  const int i  = t & 63;
  const int cg = t >> 6;

  __shared__ float Kt[64 * 64];
  __shared__ float Vt[64 * 64];
  __shared__ float Sld[64 * 64];
  __shared__ float redmax[4 * 64];
  __shared__ float redsum[4 * 64];

  const float scale = 0.03608439182435161f;  // 1/sqrt(768)

  float4 q4[16];
  {
    const float4* qrow = (const float4*)(qg + ((size_t)b * T + qt * 64 + i) * D);
    #pragma unroll
    for (int dc = 0; dc < 16; ++dc) q4[dc] = qrow[dc];
  }

  float4 O4[4];
  #pragma unroll
  for (int c = 0; c < 4; ++c) O4[c] = make_float4(0.f, 0.f, 0.f, 0.f);
  float mo = -1e30f, l = 0.f;

  for (int kt = 0; kt <= qt; ++kt) {
    __syncthreads();
    {
      const float4* kb = (const float4*)(kg + ((size_t)b * T + kt * 64) * D);
      const float4* vb = (const float4*)(vg + ((size_t)b * T + kt * 64) * D);
      float4* kl = (float4*)Kt;
      float4* vl = (float4*)Vt;
      #pragma unroll
      for (int r = 0; r < 4; ++r) {
        kl[r * 256 + t] = kb[r * 256 + t];
        vl[r * 256 + t] = vb[r * 256 + t];
      }
    }
    __syncthreads();

    float sc[16];
    float pmax = -1e30f;
    const bool diag = (kt == qt);
    #pragma unroll
    for (int jj = 0; jj < 16; ++jj) {
      const int j = cg * 16 + jj;
      const float4* kr = (const float4*)(Kt + j * 64);
      float a = 0.f;
      #pragma unroll
      for (int dc = 0; dc < 16; ++dc) {
        float4 k4 = kr[dc];
        a = fmaf(q4[dc].x, k4.x, a);
        a = fmaf(q4[dc].y, k4.y, a);
        a = fmaf(q4[dc].z, k4.z, a);
        a = fmaf(q4[dc].w, k4.w, a);
      }
      a *= scale;
      if (diag && j > i) a = -1e30f;
      sc[jj] = a;
      pmax = fmaxf(pmax, a);
    }

    redmax[cg * 64 + i] = pmax;
    __syncthreads();
    float mt = fmaxf(fmaxf(redmax[0 * 64 + i], redmax[1 * 64 + i]),
                     fmaxf(redmax[2 * 64 + i], redmax[3 * 64 + i]));
    float mn = fmaxf(mo, mt);
    float alpha = __expf(mo - mn);
    float psum = 0.f;
    #pragma unroll
    for (int jj = 0; jj < 16; ++jj) {
      float p = __expf(sc[jj] - mn);
      psum += p;
      Sld[(cg * 16 + jj) * 64 + i] = p;
    }
    redsum[cg * 64 + i] = psum;
    __syncthreads();
    l = alpha * l + (redsum[0 * 64 + i] + redsum[1 * 64 + i] +
                     redsum[2 * 64 + i] + redsum[3 * 64 + i]);
    mo = mn;
    #pragma unroll
    for (int c = 0; c < 4; ++c) {
      O4[c].x *= alpha; O4[c].y *= alpha; O4[c].z *= alpha; O4[c].w *= alpha;
    }

    for (int j = 0; j < 64; ++j) {
      float p = Sld[j * 64 + i];
      const float4* vr = (const float4*)(Vt + j * 64 + cg * 16);
      #pragma unroll
      for (int c = 0; c < 4; ++c) {
        float4 v4 = vr[c];
        O4[c].x = fmaf(p, v4.x, O4[c].x);
        O4[c].y = fmaf(p, v4.y, O4[c].y);
        O4[c].z = fmaf(p, v4.z, O4[c].z);
        O4[c].w = fmaf(p, v4.w, O4[c].w);
      }
    }
  }

  const float inv = 1.f / l;
  float4* orow = (float4*)(out + ((size_t)b * T + qt * 64 + i) * D + cg * 16);
  #pragma unroll
  for (int c = 0; c < 4; ++c) {
    float4 o = O4[c];
    o.x *= inv; o.y *= inv; o.z *= inv; o.w *= inv;
    orow[c] = o;
  }
}

// ---------------------------------------------------------------------------
extern "C" void kernel_launch(void* const* d_in, const int* in_sizes, int n_in,
                              void* d_out, int out_size, void* d_ws, size_t ws_size,
                              hipStream_t stream) {
  const float* x  = (const float*)d_in[0];
  const float* Wq = (const float*)d_in[1];
  const float* Wk = (const float*)d_in[2];
  const float* Wv = (const float*)d_in[3];
  float* outp = (float*)d_out;
  float* qkv  = (float*)d_ws;   // 3*B*T*D*4 = 25.2 MB scratch

  proj_mfma<<<dim3((B * T) / 128, 3), dim3(256), 0, stream>>>(x, Wq, Wk, Wv, qkv);
  attn<<<dim3(T / 64, B), dim3(256), 0, stream>>>(
      qkv, qkv + (size_t)B * T * D, qkv + 2 * (size_t)B * T * D, outp);
}

// Round 3
// 247.699 us; speedup vs baseline: 4.4736x; 1.9001x over previous
//
#include <hip/hip_runtime.h>
#include <cmath>

#define B 32
#define T 1024
#define CDIM 768
#define D 64
#define SCALE 0.03608439182435161f   // 1/sqrt(768), folded into Q at proj time

typedef short bf16x8 __attribute__((ext_vector_type(8)));   // 8 bf16 = 4 VGPRs
typedef float f32x4 __attribute__((ext_vector_type(4)));    // MFMA accumulator
typedef unsigned short u16x8 __attribute__((ext_vector_type(8)));

__device__ inline ushort f2bf(float f) {
  union { float f; unsigned u; } v{f};
  unsigned r = (v.u + 0x7FFFu + ((v.u >> 16) & 1u)) >> 16;  // RNE
  return (ushort)r;
}

// ---------------------------------------------------------------------------
// Kernel 1: QKV projection as bf16 MFMA GEMM + fused RoPE, bf16 output.
// grid = (256, 3 [q,k,v]); block = 256 = 4 waves; 128x64 tile per block.
// Q output is pre-scaled by 1/sqrt(768). W transpose staged via in-register
// 4x4 transpose + ds_write_b64 (R2's scattered u16 stores were ~16-way
// bank-conflicted).
// ---------------------------------------------------------------------------
#define XSTR 72   // stride 72 ushorts = 144 B rows: 16B-aligned, m97-pattern
__global__ __launch_bounds__(256) void proj_mfma(
    const float* __restrict__ x,
    const float* __restrict__ Wq,
    const float* __restrict__ Wk,
    const float* __restrict__ Wv,
    ushort* __restrict__ qkv)   // [3][B*T][D] bf16
{
  const int t    = threadIdx.x;
  const int lane = t & 63;
  const int wid  = t >> 6;
  const int ln16 = lane & 15;
  const int quad = lane >> 4;
  const int sel  = blockIdx.y;
  const int row0 = blockIdx.x * 128;
  const float* W = (sel == 0) ? Wq : (sel == 1) ? Wk : Wv;

  __shared__ ushort Xs[128 * XSTR];
  __shared__ ushort Ws[64 * XSTR];

  f32x4 acc[2][4];
  #pragma unroll
  for (int mt = 0; mt < 2; ++mt)
    #pragma unroll
    for (int nt = 0; nt < 4; ++nt)
      acc[mt][nt] = (f32x4){0.f, 0.f, 0.f, 0.f};

  for (int stage = 0; stage < CDIM / 64; ++stage) {
    const int k0 = stage * 64;
    __syncthreads();

    // --- stage x chunk: 128 rows x 64 k, fp32 -> bf16 ---
    #pragma unroll
    for (int it = 0; it < 8; ++it) {
      int slot = it * 256 + t;
      int row  = slot >> 4;
      int kq   = slot & 15;
      float4 xv = *(const float4*)(x + (size_t)(row0 + row) * CDIM + k0 + kq * 4);
      ushort4 bv;
      bv.x = f2bf(xv.x); bv.y = f2bf(xv.y); bv.z = f2bf(xv.z); bv.w = f2bf(xv.w);
      *(ushort4*)&Xs[row * XSTR + kq * 4] = bv;
    }
    // --- stage W chunk transposed via in-register 4x4: Wt[n][k] ---
    {
      int kb = t >> 4, nb = t & 15;          // k0l = kb*4, n0 = nb*4
      float wr[4][4];
      #pragma unroll
      for (int i = 0; i < 4; ++i)
        *(float4*)wr[i] = *(const float4*)(W + (size_t)(k0 + kb * 4 + i) * D + nb * 4);
      #pragma unroll
      for (int j = 0; j < 4; ++j) {
        ushort4 c;
        c.x = f2bf(wr[0][j]); c.y = f2bf(wr[1][j]);
        c.z = f2bf(wr[2][j]); c.w = f2bf(wr[3][j]);
        *(ushort4*)&Ws[(nb * 4 + j) * XSTR + kb * 4] = c;
      }
    }
    __syncthreads();

    #pragma unroll
    for (int ks = 0; ks < 2; ++ks) {
      const int koff = ks * 32 + quad * 8;
      bf16x8 a[2], bb[4];
      #pragma unroll
      for (int mt = 0; mt < 2; ++mt)
        a[mt] = *(const bf16x8*)&Xs[(wid * 32 + mt * 16 + ln16) * XSTR + koff];
      #pragma unroll
      for (int nt = 0; nt < 4; ++nt)
        bb[nt] = *(const bf16x8*)&Ws[(nt * 16 + ln16) * XSTR + koff];
      #pragma unroll
      for (int mt = 0; mt < 2; ++mt)
        #pragma unroll
        for (int nt = 0; nt < 4; ++nt)
          acc[mt][nt] = __builtin_amdgcn_mfma_f32_16x16x32_bf16(
              a[mt], bb[nt], acc[mt][nt], 0, 0, 0);
    }
  }

  // --- epilogue: RoPE (sel<2), Q pre-scale, bf16 store ---
  ushort* outbase = qkv + (size_t)sel * (B * T * D);
  #pragma unroll
  for (int mt = 0; mt < 2; ++mt) {
    #pragma unroll
    for (int nt = 0; nt < 4; ++nt) {
      const int d = nt * 16 + ln16;
      if (sel < 2) {
        const float freq = __expf((float)(d & 62) * (-0.14391156855801f));
        const float sgn  = (d & 1) ? 1.f : -1.f;
        #pragma unroll
        for (int reg = 0; reg < 4; ++reg) {
          int rowg = row0 + wid * 32 + mt * 16 + quad * 4 + reg;
          int tpos = rowg & (T - 1);
          float theta = (float)tpos * freq;
          float s = sinf(theta), c = cosf(theta);
          float val = acc[mt][nt][reg];
          float partner = __shfl_xor(val, 1, 64);
          float r = fmaf(sgn * partner, s, val * c);
          if (sel == 0) r *= SCALE;
          outbase[(size_t)rowg * D + d] = f2bf(r);
        }
      } else {
        #pragma unroll
        for (int reg = 0; reg < 4; ++reg) {
          int rowg = row0 + wid * 32 + mt * 16 + quad * 4 + reg;
          outbase[(size_t)rowg * D + d] = f2bf(acc[mt][nt][reg]);
        }
      }
    }
  }
}

// ---------------------------------------------------------------------------
// Kernel 2: causal flash attention, bf16 MFMA.
// grid = (16, 32), block = 256 = 4 waves; 64-row q-tile, wave w owns queries
// wid*16..+16. S^T = K·Q^T so C-layout n (=ln16) is the QUERY: softmax
// reductions are 2 shfl_xor, and P lands lane-aligned for ds_write_b64 ->
// ds_read_b128 into PV's A-operand. V staged transposed (Vt[d][key]) via
// in-register 4x4 so PV B-frags are contiguous b128 reads.
// LPT: qt = 15-blockIdx.x launches the long (qt+1)-iteration blocks first.
// ---------------------------------------------------------------------------
__global__ __launch_bounds__(256) void attn_mfma(
    const ushort* __restrict__ qg,
    const ushort* __restrict__ kg,
    const ushort* __restrict__ vg,
    float* __restrict__ out)
{
  const int t    = threadIdx.x;
  const int lane = t & 63;
  const int wid  = t >> 6;
  const int ln16 = lane & 15;
  const int quad = lane >> 4;
  const int qt   = 15 - blockIdx.x;   // LPT scheduling
  const int b    = blockIdx.y;

  __shared__ ushort Ks[64 * XSTR];   // [key][d]
  __shared__ ushort Vt[64 * XSTR];   // [d][key]  (transposed)
  __shared__ ushort Pl[64 * XSTR];   // [q][key], wave w owns rows 16w..16w+15

  // Q B-frags: B[k=d][n=q=ln16] -> 8 contiguous d at row wid*16+ln16. Once.
  bf16x8 qf[2];
  {
    const ushort* qrow = qg + (size_t)(b * T + qt * 64 + wid * 16 + ln16) * D;
    qf[0] = *(const bf16x8*)(qrow + quad * 8);
    qf[1] = *(const bf16x8*)(qrow + quad * 8 + 32);
  }

  f32x4 O[4];
  #pragma unroll
  for (int nt = 0; nt < 4; ++nt) O[nt] = (f32x4){0.f, 0.f, 0.f, 0.f};
  float mo = -1e30f, l = 0.f;

  for (int kt = 0; kt <= qt; ++kt) {
    __syncthreads();   // prior Ks/Vt readers done
    // --- stage K tile [64 keys][64 d], 16B slots ---
    #pragma unroll
    for (int i = 0; i < 2; ++i) {
      int slot = i * 256 + t;
      int row = slot >> 3, dblk = slot & 7;
      *(u16x8*)&Ks[row * XSTR + dblk * 8] =
          *(const u16x8*)(kg + (size_t)(b * T + kt * 64 + row) * D + dblk * 8);
    }
    // --- stage V transposed via in-register 4x4 ---
    {
      int dblk = t & 15, kb = t >> 4;
      int d0 = dblk * 4, kk0 = kb * 4;
      ushort rr[4][4];
      #pragma unroll
      for (int i = 0; i < 4; ++i)
        *(ushort4*)rr[i] = *(const ushort4*)(vg + (size_t)(b * T + kt * 64 + kk0 + i) * D + d0);
      #pragma unroll
      for (int j = 0; j < 4; ++j) {
        ushort4 c;
        c.x = rr[0][j]; c.y = rr[1][j]; c.z = rr[2][j]; c.w = rr[3][j];
        *(ushort4*)&Vt[(d0 + j) * XSTR + kk0] = c;
      }
    }
    __syncthreads();

    // --- S^T[key][q] = K · Q^T : A=K-frag (m=key,k=d), B=Q-frag ---
    f32x4 s[4];
    #pragma unroll
    for (int mt = 0; mt < 4; ++mt) s[mt] = (f32x4){0.f, 0.f, 0.f, 0.f};
    #pragma unroll
    for (int ks = 0; ks < 2; ++ks) {
      #pragma unroll
      for (int mt = 0; mt < 4; ++mt) {
        bf16x8 kf = *(const bf16x8*)&Ks[(mt * 16 + ln16) * XSTR + quad * 8 + ks * 32];
        s[mt] = __builtin_amdgcn_mfma_f32_16x16x32_bf16(kf, qf[ks], s[mt], 0, 0, 0);
      }
    }

    // --- causal mask on diagonal tile: key_local > q_local ---
    if (kt == qt) {
      const int ql = wid * 16 + ln16;
      #pragma unroll
      for (int mt = 0; mt < 4; ++mt)
        #pragma unroll
        for (int reg = 0; reg < 4; ++reg)
          if (mt * 16 + quad * 4 + reg > ql) s[mt][reg] = -1e30f;
    }

    // --- online softmax: lane holds 16 keys of query q=ln16 ---
    float tmax = -1e30f;
    #pragma unroll
    for (int mt = 0; mt < 4; ++mt)
      #pragma unroll
      for (int reg = 0; reg < 4; ++reg) tmax = fmaxf(tmax, s[mt][reg]);
    tmax = fmaxf(tmax, __shfl_xor(tmax, 16, 64));
    tmax = fmaxf(tmax, __shfl_xor(tmax, 32, 64));
    float mn = fmaxf(mo, tmax);
    float alpha = __expf(mo - mn);
    float psum = 0.f;
    #pragma unroll
    for (int mt = 0; mt < 4; ++mt) {
      float p0 = __expf(s[mt][0] - mn), p1 = __expf(s[mt][1] - mn);
      float p2 = __expf(s[mt][2] - mn), p3 = __expf(s[mt][3] - mn);
      psum += (p0 + p1) + (p2 + p3);
      ushort4 pk;
      pk.x = f2bf(p0); pk.y = f2bf(p1); pk.z = f2bf(p2); pk.w = f2bf(p3);
      // P[q=ln16][keys mt*16+quad*4 ..+4] -> wave-private region, no barrier
      *(ushort4*)&Pl[(wid * 16 + ln16) * XSTR + mt * 16 + quad * 4] = pk;
    }
    psum += __shfl_xor(psum, 16, 64);
    psum += __shfl_xor(psum, 32, 64);
    l = alpha * l + psum;
    mo = mn;

    // --- rescale O: alpha lives at lane q; O rows are q=quad*4+reg ---
    #pragma unroll
    for (int reg = 0; reg < 4; ++reg) {
      float av = __shfl(alpha, quad * 4 + reg, 64);
      #pragma unroll
      for (int nt = 0; nt < 4; ++nt) O[nt][reg] *= av;
    }

    // --- PV: A = P (m=q,k=key), B = Vt-frag (k=key,n=d) ---
    bf16x8 pa[2];
    pa[0] = *(const bf16x8*)&Pl[(wid * 16 + ln16) * XSTR + quad * 8];
    pa[1] = *(const bf16x8*)&Pl[(wid * 16 + ln16) * XSTR + quad * 8 + 32];
    #pragma unroll
    for (int ks = 0; ks < 2; ++ks) {
      #pragma unroll
      for (int nt = 0; nt < 4; ++nt) {
        bf16x8 vf = *(const bf16x8*)&Vt[(nt * 16 + ln16) * XSTR + quad * 8 + ks * 32];
        O[nt] = __builtin_amdgcn_mfma_f32_16x16x32_bf16(pa[ks], vf, O[nt], 0, 0, 0);
      }
    }
  }

  // --- epilogue: O[q=quad*4+reg][d=nt*16+ln16] * (1/l[q]) ---
  float inv = 1.f / l;
  #pragma unroll
  for (int reg = 0; reg < 4; ++reg) {
    float iv = __shfl(inv, quad * 4 + reg, 64);
    size_t row = (size_t)(b * T + qt * 64 + wid * 16 + quad * 4 + reg) * D;
    #pragma unroll
    for (int nt = 0; nt < 4; ++nt)
      out[row + nt * 16 + ln16] = O[nt][reg] * iv;
  }
}

// ---------------------------------------------------------------------------
extern "C" void kernel_launch(void* const* d_in, const int* in_sizes, int n_in,
                              void* d_out, int out_size, void* d_ws, size_t ws_size,
                              hipStream_t stream) {
  const float* x  = (const float*)d_in[0];
  const float* Wq = (const float*)d_in[1];
  const float* Wk = (const float*)d_in[2];
  const float* Wv = (const float*)d_in[3];
  float* outp = (float*)d_out;
  ushort* qkv = (ushort*)d_ws;   // 3*B*T*D*2 = 12.6 MB bf16 scratch

  proj_mfma<<<dim3((B * T) / 128, 3), dim3(256), 0, stream>>>(x, Wq, Wk, Wv, qkv);
  attn_mfma<<<dim3(T / 64, B), dim3(256), 0, stream>>>(
      qkv, qkv + (size_t)B * T * D, qkv + 2 * (size_t)B * T * D, outp);
}

// Round 4
// 186.711 us; speedup vs baseline: 5.9349x; 1.3266x over previous
//
#include <hip/hip_runtime.h>
#include <cmath>

#define B 32
#define T 1024
#define CDIM 768
#define D 64
#define SCALE 0.03608439182435161f   // 1/sqrt(768), folded into Wq at prep
#define XSTR 72                      // LDS row stride (ushort): 144B, 16B-aligned

typedef short bf16x8 __attribute__((ext_vector_type(8)));
typedef float f32x4 __attribute__((ext_vector_type(4)));
typedef unsigned short u16x8 __attribute__((ext_vector_type(8)));

__device__ inline ushort f2bf(float f) {
  union { float f; unsigned u; } v{f};
  unsigned r = (v.u + 0x7FFFu + ((v.u >> 16) & 1u)) >> 16;  // RNE
  return (ushort)r;
}

// ---------------------------------------------------------------------------
// Kernel 0: one-time W transpose + bf16 cvt: Wt[n=sel*64+col][k] = W_sel[k][col]
// (Wq pre-scaled by 1/sqrt(768); commutes with RoPE since rotation is linear.)
// ---------------------------------------------------------------------------
__global__ __launch_bounds__(256) void wt_prep(
    const float* __restrict__ Wq, const float* __restrict__ Wk,
    const float* __restrict__ Wv, ushort* __restrict__ Wt)
{
  const int n   = blockIdx.x;          // 0..191
  const int sel = n >> 6, col = n & 63;
  const float* W = (sel == 0) ? Wq : (sel == 1) ? Wk : Wv;
  const float sc = (sel == 0) ? SCALE : 1.f;
  for (int k = threadIdx.x; k < CDIM; k += 256)
    Wt[(size_t)n * CDIM + k] = f2bf(W[(size_t)k * D + col] * sc);
}

// ---------------------------------------------------------------------------
// Kernel 1: fused QKV projection GEMM (N=192) + RoPE, bf16 out.
// grid = 512 (64 rows each), block = 256 = 4 waves; wave w owns rows w*16..+16,
// all 192 cols = 12 n-tiles of mfma_f32_16x16x32_bf16.
// Software pipeline: double-buffered LDS, ONE barrier/stage; stage s+1's
// global loads are issued before the barrier so their latency hides behind
// the barrier + MFMA of stage s.
// ---------------------------------------------------------------------------
__global__ __launch_bounds__(256) void proj_mfma(
    const float* __restrict__ x,
    const ushort* __restrict__ Wt,
    ushort* __restrict__ qkv)          // [3][B*T][D] bf16
{
  const int t    = threadIdx.x;
  const int lane = t & 63;
  const int wid  = t >> 6;
  const int ln16 = lane & 15;
  const int quad = lane >> 4;
  const int row0 = blockIdx.x * 64;

  __shared__ ushort Xs[2][64 * XSTR];    // 2 x 9216 B
  __shared__ ushort Ws[2][192 * XSTR];   // 2 x 27648 B  (total 73.7 KB -> 2 blk/CU)

  f32x4 acc[12];
  #pragma unroll
  for (int nt = 0; nt < 12; ++nt) acc[nt] = (f32x4){0.f, 0.f, 0.f, 0.f};

  float4 xp[4];   // x prefetch (fp32, cvt at LDS-write time)
  u16x8  wp[6];   // Wt prefetch (already bf16)

  auto load_stage = [&](int s) {
    const int k0 = s * 64;
    #pragma unroll
    for (int it = 0; it < 4; ++it) {
      int slot = it * 256 + t, row = slot >> 4, kq = slot & 15;
      xp[it] = *(const float4*)(x + (size_t)(row0 + row) * CDIM + k0 + kq * 4);
    }
    #pragma unroll
    for (int it = 0; it < 6; ++it) {
      int slot = it * 256 + t, n = slot >> 3, kb = slot & 7;
      wp[it] = *(const u16x8*)(Wt + (size_t)n * CDIM + k0 + kb * 8);
    }
  };

  load_stage(0);
  int buf = 0;
  for (int s = 0; s < CDIM / 64; ++s) {
    // write stage s regs -> LDS buf
    #pragma unroll
    for (int it = 0; it < 4; ++it) {
      int slot = it * 256 + t, row = slot >> 4, kq = slot & 15;
      ushort4 bv;
      bv.x = f2bf(xp[it].x); bv.y = f2bf(xp[it].y);
      bv.z = f2bf(xp[it].z); bv.w = f2bf(xp[it].w);
      *(ushort4*)&Xs[buf][row * XSTR + kq * 4] = bv;
    }
    #pragma unroll
    for (int it = 0; it < 6; ++it) {
      int slot = it * 256 + t, n = slot >> 3, kb = slot & 7;
      *(u16x8*)&Ws[buf][n * XSTR + kb * 8] = wp[it];
    }
    if (s < CDIM / 64 - 1) load_stage(s + 1);   // in flight across barrier+MFMA
    __syncthreads();                             // single barrier per stage

    #pragma unroll
    for (int ks = 0; ks < 2; ++ks) {
      bf16x8 a = *(const bf16x8*)&Xs[buf][(wid * 16 + ln16) * XSTR + ks * 32 + quad * 8];
      #pragma unroll
      for (int nt = 0; nt < 12; ++nt) {
        bf16x8 bb = *(const bf16x8*)&Ws[buf][(nt * 16 + ln16) * XSTR + ks * 32 + quad * 8];
        acc[nt] = __builtin_amdgcn_mfma_f32_16x16x32_bf16(a, bb, acc[nt], 0, 0, 0);
      }
    }
    buf ^= 1;
  }

  // epilogue: C/D col=ln16, row=quad*4+reg; sel = nt>>2, d = (nt&3)*16+ln16
  #pragma unroll
  for (int nt = 0; nt < 12; ++nt) {
    const int sel = nt >> 2;
    const int d   = (nt & 3) * 16 + ln16;
    ushort* outb = qkv + (size_t)sel * (B * T * D);
    if (sel < 2) {
      const float freq = __expf((float)(d & 62) * (-0.14391156855801f));
      const float sgn  = (d & 1) ? 1.f : -1.f;
      #pragma unroll
      for (int reg = 0; reg < 4; ++reg) {
        int rowg = row0 + wid * 16 + quad * 4 + reg;
        float s, c;
        __sincosf((float)(rowg & (T - 1)) * freq, &s, &c);
        float val = acc[nt][reg];
        float partner = __shfl_xor(val, 1, 64);
        outb[(size_t)rowg * D + d] = f2bf(fmaf(sgn * partner, s, val * c));
      }
    } else {
      #pragma unroll
      for (int reg = 0; reg < 4; ++reg) {
        int rowg = row0 + wid * 16 + quad * 4 + reg;
        outb[(size_t)rowg * D + d] = f2bf(acc[nt][reg]);
      }
    }
  }
}

// ---------------------------------------------------------------------------
// Kernel 2: causal flash attention, bf16 MFMA, software-pipelined.
// S^T = K·Q^T formulation (R3-validated). Double-buffered Ks/Vt, ONE barrier
// per kt; next tile's K/V prefetched into regs during current compute.
// Vt staging remapped: consecutive lanes = key columns -> conflict-free-ish
// LDS writes (global reads strided but L2-resident). LPT: qt = 15-bx.
// ---------------------------------------------------------------------------
__global__ __launch_bounds__(256) void attn_mfma(
    const ushort* __restrict__ qg,
    const ushort* __restrict__ kg,
    const ushort* __restrict__ vg,
    float* __restrict__ out)
{
  const int t    = threadIdx.x;
  const int lane = t & 63;
  const int wid  = t >> 6;
  const int ln16 = lane & 15;
  const int quad = lane >> 4;
  const int qt   = 15 - (int)blockIdx.x;   // LPT
  const int b    = blockIdx.y;

  __shared__ ushort Ks[2][64 * XSTR];
  __shared__ ushort Vt[2][64 * XSTR];
  __shared__ ushort Pl[64 * XSTR];         // wave-private rows, reused each kt

  // Q B-frags (n=q=ln16, k=d contiguous), loaded once
  bf16x8 qf[2];
  {
    const ushort* qrow = qg + (size_t)(b * T + qt * 64 + wid * 16 + ln16) * D;
    qf[0] = *(const bf16x8*)(qrow + quad * 8);
    qf[1] = *(const bf16x8*)(qrow + quad * 8 + 32);
  }

  f32x4 O[4];
  #pragma unroll
  for (int nt = 0; nt < 4; ++nt) O[nt] = (f32x4){0.f, 0.f, 0.f, 0.f};
  float mo = -1e30f, l = 0.f;

  const int kb = t & 15, db = t >> 4;      // V staging mapping
  const int d0 = db * 4, kk0 = kb * 4;

  u16x8  kp[2];
  ushort4 vp[4];
  auto load_kv = [&](int kt) {
    #pragma unroll
    for (int i = 0; i < 2; ++i) {
      int slot = i * 256 + t, row = slot >> 3, dblk = slot & 7;
      kp[i] = *(const u16x8*)(kg + (size_t)(b * T + kt * 64 + row) * D + dblk * 8);
    }
    #pragma unroll
    for (int i = 0; i < 4; ++i)
      vp[i] = *(const ushort4*)(vg + (size_t)(b * T + kt * 64 + kk0 + i) * D + d0);
  };

  load_kv(0);
  int buf = 0;
  for (int kt = 0; kt <= qt; ++kt) {
    // write prefetched tile -> LDS buf
    #pragma unroll
    for (int i = 0; i < 2; ++i) {
      int slot = i * 256 + t, row = slot >> 3, dblk = slot & 7;
      *(u16x8*)&Ks[buf][row * XSTR + dblk * 8] = kp[i];
    }
    const ushort* vpe = (const ushort*)vp;
    #pragma unroll
    for (int j = 0; j < 4; ++j) {
      ushort4 c;
      c.x = vpe[0 * 4 + j]; c.y = vpe[1 * 4 + j];
      c.z = vpe[2 * 4 + j]; c.w = vpe[3 * 4 + j];
      *(ushort4*)&Vt[buf][(d0 + j) * XSTR + kk0] = c;   // lanes consecutive in kk0
    }
    if (kt < qt) load_kv(kt + 1);
    __syncthreads();                                     // single barrier per kt

    // --- S^T[key][q] = K·Q^T ---
    f32x4 s[4];
    #pragma unroll
    for (int mt = 0; mt < 4; ++mt) s[mt] = (f32x4){0.f, 0.f, 0.f, 0.f};
    #pragma unroll
    for (int ks = 0; ks < 2; ++ks)
      #pragma unroll
      for (int mt = 0; mt < 4; ++mt) {
        bf16x8 kf = *(const bf16x8*)&Ks[buf][(mt * 16 + ln16) * XSTR + quad * 8 + ks * 32];
        s[mt] = __builtin_amdgcn_mfma_f32_16x16x32_bf16(kf, qf[ks], s[mt], 0, 0, 0);
      }

    if (kt == qt) {              // causal mask, diagonal tile only
      const int ql = wid * 16 + ln16;
      #pragma unroll
      for (int mt = 0; mt < 4; ++mt)
        #pragma unroll
        for (int reg = 0; reg < 4; ++reg)
          if (mt * 16 + quad * 4 + reg > ql) s[mt][reg] = -1e30f;
    }

    // --- online softmax (lane = q, holds 16 keys) ---
    float tmax = -1e30f;
    #pragma unroll
    for (int mt = 0; mt < 4; ++mt)
      #pragma unroll
      for (int reg = 0; reg < 4; ++reg) tmax = fmaxf(tmax, s[mt][reg]);
    tmax = fmaxf(tmax, __shfl_xor(tmax, 16, 64));
    tmax = fmaxf(tmax, __shfl_xor(tmax, 32, 64));
    float mn = fmaxf(mo, tmax);
    float alpha = __expf(mo - mn);
    float psum = 0.f;
    #pragma unroll
    for (int mt = 0; mt < 4; ++mt) {
      float p0 = __expf(s[mt][0] - mn), p1 = __expf(s[mt][1] - mn);
      float p2 = __expf(s[mt][2] - mn), p3 = __expf(s[mt][3] - mn);
      psum += (p0 + p1) + (p2 + p3);
      ushort4 pk;
      pk.x = f2bf(p0); pk.y = f2bf(p1); pk.z = f2bf(p2); pk.w = f2bf(p3);
      *(ushort4*)&Pl[(wid * 16 + ln16) * XSTR + mt * 16 + quad * 4] = pk;
    }
    psum += __shfl_xor(psum, 16, 64);
    psum += __shfl_xor(psum, 32, 64);
    l = alpha * l + psum;
    mo = mn;

    #pragma unroll
    for (int reg = 0; reg < 4; ++reg) {
      float av = __shfl(alpha, quad * 4 + reg, 64);
      #pragma unroll
      for (int nt = 0; nt < 4; ++nt) O[nt][reg] *= av;
    }

    // --- PV ---
    bf16x8 pa[2];
    pa[0] = *(const bf16x8*)&Pl[(wid * 16 + ln16) * XSTR + quad * 8];
    pa[1] = *(const bf16x8*)&Pl[(wid * 16 + ln16) * XSTR + quad * 8 + 32];
    #pragma unroll
    for (int ks = 0; ks < 2; ++ks)
      #pragma unroll
      for (int nt = 0; nt < 4; ++nt) {
        bf16x8 vf = *(const bf16x8*)&Vt[buf][(nt * 16 + ln16) * XSTR + quad * 8 + ks * 32];
        O[nt] = __builtin_amdgcn_mfma_f32_16x16x32_bf16(pa[ks], vf, O[nt], 0, 0, 0);
      }
    buf ^= 1;
  }

  float inv = 1.f / l;
  #pragma unroll
  for (int reg = 0; reg < 4; ++reg) {
    float iv = __shfl(inv, quad * 4 + reg, 64);
    size_t row = (size_t)(b * T + qt * 64 + wid * 16 + quad * 4 + reg) * D;
    #pragma unroll
    for (int nt = 0; nt < 4; ++nt)
      out[row + nt * 16 + ln16] = O[nt][reg] * iv;
  }
}

// ---------------------------------------------------------------------------
extern "C" void kernel_launch(void* const* d_in, const int* in_sizes, int n_in,
                              void* d_out, int out_size, void* d_ws, size_t ws_size,
                              hipStream_t stream) {
  const float* x  = (const float*)d_in[0];
  const float* Wq = (const float*)d_in[1];
  const float* Wk = (const float*)d_in[2];
  const float* Wv = (const float*)d_in[3];
  float* outp = (float*)d_out;

  ushort* qkv = (ushort*)d_ws;                         // 12.58 MB bf16
  ushort* Wt  = qkv + (size_t)3 * B * T * D;           // +288 KB bf16

  wt_prep<<<dim3(192), dim3(256), 0, stream>>>(Wq, Wk, Wv, Wt);
  proj_mfma<<<dim3((B * T) / 64), dim3(256), 0, stream>>>(x, Wt, qkv);
  attn_mfma<<<dim3(T / 64, B), dim3(256), 0, stream>>>(
      qkv, qkv + (size_t)B * T * D, qkv + 2 * (size_t)B * T * D, outp);
}